// Round 13
// baseline (194.561 us; speedup 1.0000x reference)
//
#include <hip/hip_runtime.h>
#include <hip/hip_bf16.h>
#include <math.h>

typedef float v2f __attribute__((ext_vector_type(2)));
typedef float v4f __attribute__((ext_vector_type(4)));

// Problem constants
#define NQ1 1001      // NQ+1 rows in embed tables
#define KK 5
#define MM 50
#define KD 64
#define VD 64
#define SD 50
#define BB 512
#define SS 500

#define NW 8          // waves per scan block
#define WIN 8         // scan steps per window
#define NWIN 62       // full windows (62*8 = 496; tail = 4 steps)

// Workspace layout (in floats)
#define OFF_ATTN   0                        // [1001][64] attn rows, cols 50..63 = 0
#define OFF_SQ     (OFF_ATTN + NQ1*64)      // [1001][64] q_embed @ Ws[64:128]
#define OFF_EAD    (OFF_SQ   + NQ1*64)      // [5005][128] interleaved (e,ad) per v
#define OFF_WST    (OFF_EAD  + NQ1*KK*128)  // [50][64] transposed top of Ws
#define OFF_WCT    (OFF_WST  + SD*64)       // [5][50] transposed Wc (pad to 256)
#define OFF_READS  (OFF_WCT  + 256)         // [512*500][64]

#define LGKM_BARRIER() asm volatile("s_waitcnt lgkmcnt(0)\n\ts_barrier" ::: "memory")

// ---------------- kernel 1: all tables (qtab softmax+Sq, transposes, ead) ----------------
__global__ __launch_bounds__(64) void k_tabs(
    const float* __restrict__ qtab, const float* __restrict__ itab,
    const float* __restrict__ keymem,
    const float* __restrict__ Wv, const float* __restrict__ bv,
    const float* __restrict__ We, const float* __restrict__ be,
    const float* __restrict__ Wa, const float* __restrict__ ba,
    const float* __restrict__ Ws, const float* __restrict__ Wc,
    float* __restrict__ attn_tab, float* __restrict__ sq_tab,
    float* __restrict__ ead_tab, float* __restrict__ WsT, float* __restrict__ WcT) {
  const int bid = blockIdx.x;
  const int t = threadIdx.x;

  if (bid < NQ1) {  // ---- per-question: attn softmax row + sq row ----
    const int q = bid;
    __shared__ float qe[64];
    qe[t] = qtab[q * KD + t];
    __syncthreads();

    float dot = 0.f;
    if (t < MM) {
#pragma unroll
      for (int i = 0; i < KD; ++i) dot = fmaf(qe[i], keymem[t * KD + i], dot);
    }
    float xv = (t < MM) ? dot : -1e30f;
#pragma unroll
    for (int off = 32; off; off >>= 1) xv = fmaxf(xv, __shfl_xor(xv, off));
    float p = (t < MM) ? __expf(dot - xv) : 0.f;
    float sum = p;
#pragma unroll
    for (int off = 32; off; off >>= 1) sum += __shfl_xor(sum, off);
    attn_tab[q * 64 + t] = p / sum;   // pad lanes (t>=50) write 0

    float sq = 0.f;
    if (t < SD) {
#pragma unroll
      for (int i = 0; i < KD; ++i) sq = fmaf(qe[i], Ws[(64 + i) * SD + t], sq);
    }
    sq_tab[q * 64 + t] = (t < SD) ? sq : 0.f;
    return;
  }

  if (bid == NQ1) {  // ---- transposes ----
    for (int idx = t; idx < 64 * SD; idx += 64) {
      int i = idx / SD, j = idx % SD;
      WsT[j * 64 + i] = Ws[idx];
    }
    for (int idx = t; idx < SD * KK; idx += 64) {
      int j = idx / KK, c = idx % KK;
      WcT[c * SD + j] = Wc[idx];
    }
    return;
  }

  // ---- per-(q,r) erase/add, interleaved ----
  const int qr = bid - (NQ1 + 1);
  const int q = qr / KK, r = qr % KK;
  const int v = t;
  __shared__ float item[64];
  __shared__ float ves[64];
  item[v] = itab[q * KD + v];
  __syncthreads();

  float ve = bv[v];
#pragma unroll
  for (int i = 0; i < KD; ++i) ve = fmaf(item[i], Wv[i * VD + v], ve);
#pragma unroll
  for (int k = 0; k < KK; ++k) {
    float rf = fmaxf(0.f, 1.f - fabsf((float)k - (float)r) * 0.25f);
    ve = fmaf(rf, Wv[(KD + k) * VD + v], ve);
  }
  ves[v] = ve;
  __syncthreads();

  float se = be[v], sa = ba[v];
#pragma unroll
  for (int i = 0; i < VD; ++i) {
    float x = ves[i];
    se = fmaf(x, We[i * VD + v], se);
    sa = fmaf(x, Wa[i * VD + v], sa);
  }
  float ex = __expf(2.f * sa);
  ead_tab[qr * 128 + 2 * v]     = 1.f / (1.f + __expf(-se));
  ead_tab[qr * 128 + 2 * v + 1] = (ex - 1.f) / (ex + 1.f);
}

// ---------------- kernel 2: scan (R12 + ead register-ring via VMEM) ----------------
__global__ __launch_bounds__(512) void k_scan(
    const int* __restrict__ qs, const int* __restrict__ rs,
    const float* __restrict__ attn_tab, const float* __restrict__ ead_tab,
    const float* __restrict__ init_vm, float* __restrict__ reads) {
  const int b = blockIdx.x;
  const int tid = threadIdx.x;
  const int w = tid >> 6;       // wave id 0..7 (also: staging row, flush row)
  const int v = tid & 63;       // value column
  const int mbase = w * 8;
  const uint32_t v8 = v * 8;    // byte offset of lane's (e,ad) pair

  __shared__ float red[2][WIN][NW][64];    // 16 KB partial read sums
  __shared__ float abuf[2][WIN][64];       // 4 KB attn rows (m-indexed)
  __shared__ __align__(16) int sidx_e[512];// 2 KB per-step ead byte offsets

  const int* __restrict__ qb = qs + b * SS;
  const int* __restrict__ rb = rs + b * SS;
  float* __restrict__ outp = reads + (size_t)b * SS * 64;
  const char* __restrict__ edb = (const char*)ead_tab;

  // ---- stage per-step ead byte offsets (entries 500..511 clamped) ----
  {
    int idx = (tid < SS) ? tid : (SS - 1);
    int q = qb[idx], r = rb[idx];
    sidx_e[tid] = (q * KK + r) << 9;
  }

  // ---- prologue: stage window 0 attn; preload q/r for window 1 ----
  {
    int qp = qb[w];
    abuf[0][w][v] = attn_tab[qp * 64 + v];
  }
  int q1 = qb[8 + w];           // window-1 attn index (row w)

  v2f vm0, vm1, vm2, vm3;
  {
    int m = mbase;
    vm0.x = init_vm[(m + 0) * VD + v];
    vm0.y = init_vm[(m + 1) * VD + v];
    vm1.x = init_vm[(m + 2) * VD + v]; vm1.y = init_vm[(m + 3) * VD + v];
    if (m + 4 < MM) { vm2.x = init_vm[(m + 4) * VD + v]; vm2.y = init_vm[(m + 5) * VD + v]; }
    else vm2 = (v2f)(0.f);
    if (m + 6 < MM) { vm3.x = init_vm[(m + 6) * VD + v]; vm3.y = init_vm[(m + 7) * VD + v]; }
    else vm3 = (v2f)(0.f);
  }
  __syncthreads();

  // ---- ead ping-pong register rings (float2 per step) ----
  v2f edA[8], edB[8];
  {
    int4 o0 = *(const int4*)&sidx_e[0];
    int4 o1 = *(const int4*)&sidx_e[4];
    edA[0] = *(const v2f*)(edb + (uint32_t)o0.x + v8);
    edA[1] = *(const v2f*)(edb + (uint32_t)o0.y + v8);
    edA[2] = *(const v2f*)(edb + (uint32_t)o0.z + v8);
    edA[3] = *(const v2f*)(edb + (uint32_t)o0.w + v8);
    edA[4] = *(const v2f*)(edb + (uint32_t)o1.x + v8);
    edA[5] = *(const v2f*)(edb + (uint32_t)o1.y + v8);
    edA[6] = *(const v2f*)(edb + (uint32_t)o1.z + v8);
    edA[7] = *(const v2f*)(edb + (uint32_t)o1.w + v8);
  }

  float4 arx[2], ary[2];

#define PRELOAD(buf_) {                                              \
    const float* ab0 = &abuf[buf_][0][mbase];                        \
    arx[0] = *(const float4*)ab0;  ary[0] = *(const float4*)(ab0+4); \
    const float* ab1 = &abuf[buf_][1][mbase];                        \
    arx[1] = *(const float4*)ab1;  ary[1] = *(const float4*)(ab1+4); \
  }

#define STEP(buf_, kk, EDU) {                                        \
    float4 ax = arx[(kk)&1]; float4 ay = ary[(kk)&1];                \
    v2f ed = EDU[kk];                                                \
    if ((kk) < WIN - 2) {                                            \
      const float* abn = &abuf[buf_][(kk)+2][mbase];                 \
      arx[(kk)&1] = *(const float4*)abn;                             \
      ary[(kk)&1] = *(const float4*)(abn+4);                         \
    }                                                                \
    v2f e2 = {ed.x, ed.x}, ad2 = {ed.y, ed.y};                       \
    v2f aL0 = {ax.x, ax.y}, aL1 = {ax.z, ax.w};                      \
    v2f aH0 = {ay.x, ay.y}, aH1 = {ay.z, ay.w};                      \
    v2f acc;                                                         \
    acc  = aL0 * vm0;  vm0 += aL0 * (ad2 - e2 * vm0);                \
    acc += aL1 * vm1;  vm1 += aL1 * (ad2 - e2 * vm1);                \
    acc += aH0 * vm2;  vm2 += aH0 * (ad2 - e2 * vm2);                \
    acc += aH1 * vm3;  vm3 += aH1 * (ad2 - e2 * vm3);                \
    red[buf_][kk][w][v] = acc.x + acc.y;                             \
  }

#define FLUSH(pbuf_, baserow_) {                                     \
    float sum = 0.f;                                                 \
    _Pragma("unroll")                                                \
    for (int wv = 0; wv < NW; ++wv) sum += red[pbuf_][w][wv][v];     \
    outp[(size_t)((baserow_) + w) * 64 + v] = sum;                   \
  }

  // Window body: consume EDU ring, gather window wi_+1's ead into EDG
#define WBODY(wi_, EDU, EDG) {                                       \
    const int buf = (wi_) & 1;                                       \
    const int nb = buf ^ 1;                                          \
    PRELOAD(buf);                                                    \
    /* ead gather for window wi_+1 (VMEM, lands in regs) */          \
    { int4 o0 = *(const int4*)&sidx_e[((wi_) + 1) * 8];              \
      int4 o1 = *(const int4*)&sidx_e[((wi_) + 1) * 8 + 4];          \
      EDG[0] = *(const v2f*)(edb + (uint32_t)o0.x + v8);             \
      EDG[1] = *(const v2f*)(edb + (uint32_t)o0.y + v8);             \
      EDG[2] = *(const v2f*)(edb + (uint32_t)o0.z + v8);             \
      EDG[3] = *(const v2f*)(edb + (uint32_t)o0.w + v8);             \
      EDG[4] = *(const v2f*)(edb + (uint32_t)o1.x + v8);             \
      EDG[5] = *(const v2f*)(edb + (uint32_t)o1.y + v8);             \
      EDG[6] = *(const v2f*)(edb + (uint32_t)o1.z + v8);             \
      EDG[7] = *(const v2f*)(edb + (uint32_t)o1.w + v8); }           \
    if ((wi_) > 0) FLUSH(nb, ((wi_) - 1) * WIN);                     \
    /* attn staging issue for window wi_+1 */                        \
    float a_st = attn_tab[q1 * 64 + v];                              \
    int i2 = ((wi_) + 2) * WIN + w;                                  \
    i2 = (i2 < SS) ? i2 : (SS - 1);                                  \
    int q2 = qb[i2];                                                 \
    STEP(buf, 0, EDU); STEP(buf, 1, EDU); STEP(buf, 2, EDU);         \
    STEP(buf, 3, EDU); STEP(buf, 4, EDU); STEP(buf, 5, EDU);         \
    STEP(buf, 6, EDU); STEP(buf, 7, EDU);                            \
    abuf[nb][w][v] = a_st;                                           \
    q1 = q2;                                                         \
    LGKM_BARRIER();                                                  \
  }

  for (int wi2 = 0; wi2 < NWIN; wi2 += 2) {
    WBODY(wi2, edA, edB)
    WBODY(wi2 + 1, edB, edA)
  }

  // ---- tail: window 62 = steps 496..499, buf 0, ead in edA ----
  {
    PRELOAD(0);
    FLUSH(1, (NWIN - 1) * WIN);          // flush window 61
    STEP(0, 0, edA); STEP(0, 1, edA); STEP(0, 2, edA); STEP(0, 3, edA);
    LGKM_BARRIER();
    if (w < (SS - NWIN * WIN)) {
      float sum = 0.f;
#pragma unroll
      for (int wv = 0; wv < NW; ++wv) sum += red[0][w][wv][v];
      outp[(size_t)(NWIN * WIN + w) * 64 + v] = sum;
    }
  }
#undef WBODY
#undef PRELOAD
#undef STEP
#undef FLUSH
}

// ---------------- kernel 3: summary + logits + softmax (LDS-free) ----------------
__global__ __launch_bounds__(64) void k_out(
    const float* __restrict__ reads, const int* __restrict__ qs,
    const float* __restrict__ sq_tab, const float* __restrict__ WsT,
    const float* __restrict__ bs, const float* __restrict__ WcT,
    const float* __restrict__ bc,
    float* __restrict__ out_logits, float* __restrict__ out_probs) {
  const int lane = threadIdx.x;
  const long row = (long)blockIdx.x * 64 + lane;

  // each lane loads its own row: 16 x float4 (4 consecutive loads/64B line -> L1 hits)
  const float4* __restrict__ src = (const float4*)(reads + (size_t)row * 64);
  float x[64];
#pragma unroll
  for (int i = 0; i < 16; ++i) {
    float4 t = src[i];
    x[4 * i + 0] = t.x; x[4 * i + 1] = t.y;
    x[4 * i + 2] = t.z; x[4 * i + 3] = t.w;
  }

  const int q = qs[row];
  const float* __restrict__ sqrow = sq_tab + (long)q * 64;

  float sm[SD];
#pragma unroll
  for (int j = 0; j < SD; ++j) {
    float acc = bs[j] + sqrow[j];
    const float* __restrict__ wrow = WsT + j * 64;  // uniform -> s_load
#pragma unroll
    for (int i = 0; i < 64; ++i) acc = fmaf(x[i], wrow[i], acc);
    float ex = __expf(2.f * acc);
    sm[j] = (ex - 1.f) / (ex + 1.f);
  }

  float lg[KK];
#pragma unroll
  for (int c = 0; c < KK; ++c) {
    float acc = bc[c];
    const float* __restrict__ wrow = WcT + c * SD;  // uniform -> s_load
#pragma unroll
    for (int j = 0; j < SD; ++j) acc = fmaf(sm[j], wrow[j], acc);
    lg[c] = acc;
  }

  float mx = lg[0];
#pragma unroll
  for (int c = 1; c < KK; ++c) mx = fmaxf(mx, lg[c]);
  float p[KK], sum = 0.f;
#pragma unroll
  for (int c = 0; c < KK; ++c) { p[c] = __expf(lg[c] - mx); sum += p[c]; }
  float inv = 1.f / sum;
#pragma unroll
  for (int c = 0; c < KK; ++c) {
    out_logits[row * KK + c] = lg[c];
    out_probs[row * KK + c] = p[c] * inv;
  }
}

extern "C" void kernel_launch(void* const* d_in, const int* in_sizes, int n_in,
                              void* d_out, int out_size, void* d_ws, size_t ws_size,
                              hipStream_t stream) {
  const int*   questions  = (const int*)  d_in[0];
  const int*   responses  = (const int*)  d_in[1];
  const float* q_table    = (const float*)d_in[2];
  const float* item_table = (const float*)d_in[3];
  const float* Wv         = (const float*)d_in[4];
  const float* bv         = (const float*)d_in[5];
  const float* key_mem    = (const float*)d_in[6];
  const float* init_vm    = (const float*)d_in[7];
  const float* We         = (const float*)d_in[8];
  const float* be         = (const float*)d_in[9];
  const float* Wa         = (const float*)d_in[10];
  const float* ba         = (const float*)d_in[11];
  const float* Ws         = (const float*)d_in[12];
  const float* bs         = (const float*)d_in[13];
  const float* Wc         = (const float*)d_in[14];
  const float* bc         = (const float*)d_in[15];

  float* ws       = (float*)d_ws;
  float* attn_tab = ws + OFF_ATTN;
  float* sq_tab   = ws + OFF_SQ;
  float* ead_tab  = ws + OFF_EAD;
  float* WsT      = ws + OFF_WST;
  float* WcT      = ws + OFF_WCT;
  float* reads    = ws + OFF_READS;

  float* out_logits = (float*)d_out;
  float* out_probs  = out_logits + (size_t)BB * SS * KK;

  hipLaunchKernelGGL(k_tabs, dim3(NQ1 + 1 + NQ1 * KK), dim3(64), 0, stream,
                     q_table, item_table, key_mem, Wv, bv, We, be, Wa, ba, Ws, Wc,
                     attn_tab, sq_tab, ead_tab, WsT, WcT);
  hipLaunchKernelGGL(k_scan, dim3(BB), dim3(NW * 64), 0, stream,
                     questions, responses, attn_tab, ead_tab, init_vm, reads);
  hipLaunchKernelGGL(k_out, dim3(BB * SS / 64), dim3(64), 0, stream,
                     reads, questions, sq_tab, WsT, bs, WcT, bc,
                     out_logits, out_probs);
}

// Round 14
// 176.788 us; speedup vs baseline: 1.1005x; 1.1005x over previous
//
#include <hip/hip_runtime.h>
#include <hip/hip_bf16.h>
#include <math.h>

typedef float v2f __attribute__((ext_vector_type(2)));
typedef float f32x8 __attribute__((ext_vector_type(8)));

// Problem constants
#define NQ1 1001      // NQ+1 rows in embed tables
#define KK 5
#define MM 50
#define KD 64
#define VD 64
#define SD 50
#define BB 512
#define SS 500

#define NW 8          // waves per scan block
#define WIN 8         // scan steps per window
#define NWIN 62       // full windows (62*8 = 496; tail = 4 steps)

// Workspace layout (in floats)
#define OFF_ATTN   0                        // [1001][64] attn rows, cols 50..63 = 0
#define OFF_SQ     (OFF_ATTN + NQ1*64)      // [1001][64] q_embed @ Ws[64:128]
#define OFF_EAD    (OFF_SQ   + NQ1*64)      // [5005][128] interleaved (e,ad) per v
#define OFF_WST    (OFF_EAD  + NQ1*KK*128)  // [50][64] transposed top of Ws
#define OFF_WCT    (OFF_WST  + SD*64)       // [5][50] transposed Wc (pad to 256)
#define OFF_READS  (OFF_WCT  + 256)         // [512*500][64]

#define LGKM_BARRIER() asm volatile("s_waitcnt lgkmcnt(0)\n\ts_barrier" ::: "memory")
#define SCHED_FENCE() __builtin_amdgcn_sched_barrier(0)
#define RL(x_) __builtin_amdgcn_readfirstlane(x_)

// scalar load of one 32B attn slice: dst (8 SGPRs) <- attn_tab + byteoff
#define SLOAD(dst_, off_) \
  asm volatile("s_load_dwordx8 %0, %1, %2" : "=s"(dst_) : "s"(attn_tab), "s"(off_))

// ---------------- kernel 1: all tables (qtab softmax+Sq, transposes, ead) ----------------
__global__ __launch_bounds__(64) void k_tabs(
    const float* __restrict__ qtab, const float* __restrict__ itab,
    const float* __restrict__ keymem,
    const float* __restrict__ Wv, const float* __restrict__ bv,
    const float* __restrict__ We, const float* __restrict__ be,
    const float* __restrict__ Wa, const float* __restrict__ ba,
    const float* __restrict__ Ws, const float* __restrict__ Wc,
    float* __restrict__ attn_tab, float* __restrict__ sq_tab,
    float* __restrict__ ead_tab, float* __restrict__ WsT, float* __restrict__ WcT) {
  const int bid = blockIdx.x;
  const int t = threadIdx.x;

  if (bid < NQ1) {  // ---- per-question: attn softmax row + sq row ----
    const int q = bid;
    __shared__ float qe[64];
    qe[t] = qtab[q * KD + t];
    __syncthreads();

    float dot = 0.f;
    if (t < MM) {
#pragma unroll
      for (int i = 0; i < KD; ++i) dot = fmaf(qe[i], keymem[t * KD + i], dot);
    }
    float xv = (t < MM) ? dot : -1e30f;
#pragma unroll
    for (int off = 32; off; off >>= 1) xv = fmaxf(xv, __shfl_xor(xv, off));
    float p = (t < MM) ? __expf(dot - xv) : 0.f;
    float sum = p;
#pragma unroll
    for (int off = 32; off; off >>= 1) sum += __shfl_xor(sum, off);
    attn_tab[q * 64 + t] = p / sum;   // pad lanes (t>=50) write 0

    float sq = 0.f;
    if (t < SD) {
#pragma unroll
      for (int i = 0; i < KD; ++i) sq = fmaf(qe[i], Ws[(64 + i) * SD + t], sq);
    }
    sq_tab[q * 64 + t] = (t < SD) ? sq : 0.f;
    return;
  }

  if (bid == NQ1) {  // ---- transposes ----
    for (int idx = t; idx < 64 * SD; idx += 64) {
      int i = idx / SD, j = idx % SD;
      WsT[j * 64 + i] = Ws[idx];
    }
    for (int idx = t; idx < SD * KK; idx += 64) {
      int j = idx / KK, c = idx % KK;
      WcT[c * SD + j] = Wc[idx];
    }
    return;
  }

  // ---- per-(q,r) erase/add, interleaved ----
  const int qr = bid - (NQ1 + 1);
  const int q = qr / KK, r = qr % KK;
  const int v = t;
  __shared__ float item[64];
  __shared__ float ves[64];
  item[v] = itab[q * KD + v];
  __syncthreads();

  float ve = bv[v];
#pragma unroll
  for (int i = 0; i < KD; ++i) ve = fmaf(item[i], Wv[i * VD + v], ve);
#pragma unroll
  for (int k = 0; k < KK; ++k) {
    float rf = fmaxf(0.f, 1.f - fabsf((float)k - (float)r) * 0.25f);
    ve = fmaf(rf, Wv[(KD + k) * VD + v], ve);
  }
  ves[v] = ve;
  __syncthreads();

  float se = be[v], sa = ba[v];
#pragma unroll
  for (int i = 0; i < VD; ++i) {
    float x = ves[i];
    se = fmaf(x, We[i * VD + v], se);
    sa = fmaf(x, Wa[i * VD + v], sa);
  }
  float ex = __expf(2.f * sa);
  ead_tab[qr * 128 + 2 * v]     = 1.f / (1.f + __expf(-se));
  ead_tab[qr * 128 + 2 * v + 1] = (ex - 1.f) / (ex + 1.f);
}

// ---------------- kernel 2: scan (R12 + a-slices via scalar s_load_dwordx8) ----------------
__global__ __launch_bounds__(512) void k_scan(
    const int* __restrict__ qs, const int* __restrict__ rs,
    const float* __restrict__ attn_tab, const float* __restrict__ ead_tab,
    const float* __restrict__ init_vm, float* __restrict__ reads) {
  const int b = blockIdx.x;
  const int tid = threadIdx.x;
  const int w = tid >> 6;       // wave id 0..7 (m-slots w*8 .. w*8+7)
  const int v = tid & 63;       // value column
  const int mbase = w * 8;
  const int wb = w << 5;        // byte offset of wave's slice within a row

  __shared__ float red[2][WIN][NW][64];     // 32 KB partial read sums
  __shared__ v2f   eadbuf[2][WIN][64];      // 8 KB interleaved (e,ad) per v
  __shared__ __align__(16) int sidx_a[512]; // 2 KB per-step attn byte offsets

  const int* __restrict__ qb = qs + b * SS;
  const int* __restrict__ rb = rs + b * SS;
  float* __restrict__ outp = reads + (size_t)b * SS * 64;

  // ---- fill per-step attn byte offsets (entries 500..511 clamped) ----
  {
    int idx = (tid < SS) ? tid : (SS - 1);
    sidx_a[tid] = qb[idx] << 8;
  }

  // ---- prologue: stage window 0 ead; preload q/r ring for window 1 ----
  {
    int qp = qb[w], rp = rb[w];
    float2 ep = *(const float2*)(ead_tab + (qp * KK + rp) * 128 + 2 * v);
    eadbuf[0][w][v] = (v2f){ep.x, ep.y};
  }
  int q1 = qb[8 + w], r1 = rb[8 + w];

  v2f vm0, vm1, vm2, vm3;
  {
    int m = mbase;
    vm0.x = init_vm[(m + 0) * VD + v]; vm0.y = init_vm[(m + 1) * VD + v];
    vm1.x = init_vm[(m + 2) * VD + v]; vm1.y = init_vm[(m + 3) * VD + v];
    if (m + 4 < MM) { vm2.x = init_vm[(m + 4) * VD + v]; vm2.y = init_vm[(m + 5) * VD + v]; }
    else vm2 = (v2f)(0.f);
    if (m + 6 < MM) { vm3.x = init_vm[(m + 6) * VD + v]; vm3.y = init_vm[(m + 7) * VD + v]; }
    else vm3 = (v2f)(0.f);
  }
  __syncthreads();   // sidx_a visible to all waves

  // ---- load window-0 a-slices into SGPR buffer (8 x s_load_dwordx8) ----
  f32x8 arow[8];
  {
    int4 p0 = *(const int4*)&sidx_a[0];
    int4 p1 = *(const int4*)&sidx_a[4];
    uint32_t o0 = RL(p0.x + wb), o1 = RL(p0.y + wb);
    uint32_t o2 = RL(p0.z + wb), o3 = RL(p0.w + wb);
    uint32_t o4 = RL(p1.x + wb), o5 = RL(p1.y + wb);
    uint32_t o6 = RL(p1.z + wb), o7 = RL(p1.w + wb);
    SLOAD(arow[0], o0); SLOAD(arow[1], o1); SLOAD(arow[2], o2); SLOAD(arow[3], o3);
    SLOAD(arow[4], o4); SLOAD(arow[5], o5); SLOAD(arow[6], o6); SLOAD(arow[7], o7);
  }
  LGKM_BARRIER();   // drains s_loads + eadbuf staging
  SCHED_FENCE();

  v2f edr[2];

#define STEP(buf_, kk) {                                             \
    v2f ed = edr[(kk) & 1];                                          \
    if ((kk) < WIN - 2) edr[(kk) & 1] = eadbuf[buf_][(kk) + 2][v];   \
    v2f e2 = {ed.x, ed.x}, ad2 = {ed.y, ed.y};                       \
    v2f aL0 = {arow[kk][0], arow[kk][1]};                            \
    v2f aL1 = {arow[kk][2], arow[kk][3]};                            \
    v2f aH0 = {arow[kk][4], arow[kk][5]};                            \
    v2f aH1 = {arow[kk][6], arow[kk][7]};                            \
    v2f acc;                                                         \
    acc  = aL0 * vm0;  vm0 += aL0 * (ad2 - e2 * vm0);                \
    acc += aL1 * vm1;  vm1 += aL1 * (ad2 - e2 * vm1);                \
    acc += aH0 * vm2;  vm2 += aH0 * (ad2 - e2 * vm2);                \
    acc += aH1 * vm3;  vm3 += aH1 * (ad2 - e2 * vm3);                \
    red[buf_][kk][w][v] = acc.x + acc.y;                             \
    SLOAD(arow[kk], onext##kk);                                      \
  }

#define FLUSH(pbuf_, baserow_) {                                     \
    float sum = 0.f;                                                 \
    _Pragma("unroll")                                                \
    for (int wv = 0; wv < NW; ++wv) sum += red[pbuf_][w][wv][v];     \
    outp[(size_t)((baserow_) + w) * 64 + v] = sum;                   \
  }

  for (int wi = 0; wi < NWIN; ++wi) {
    const int buf = wi & 1;
    const int nb = buf ^ 1;

    // next-window a byte offsets (uniform b128 reads + readfirstlane)
    int4 p0 = *(const int4*)&sidx_a[(wi + 1) * 8];
    int4 p1 = *(const int4*)&sidx_a[(wi + 1) * 8 + 4];
    uint32_t onext0 = RL(p0.x + wb), onext1 = RL(p0.y + wb);
    uint32_t onext2 = RL(p0.z + wb), onext3 = RL(p0.w + wb);
    uint32_t onext4 = RL(p1.x + wb), onext5 = RL(p1.y + wb);
    uint32_t onext6 = RL(p1.z + wb), onext7 = RL(p1.w + wb);

    // edr preload for steps 0,1
    edr[0] = eadbuf[buf][0][v];
    edr[1] = eadbuf[buf][1][v];

    // flush previous window (reads red[nb]; store fire-and-forget)
    if (wi > 0) FLUSH(nb, (wi - 1) * WIN);

    // ead staging issue for window wi+1 (VMEM)
    float2 e_st = *(const float2*)(ead_tab + (q1 * KK + r1) * 128 + 2 * v);
    int i2 = (wi + 2) * WIN + w;
    i2 = (i2 < SS) ? i2 : (SS - 1);
    int q2 = qb[i2], r2 = rb[i2];

    // 8 steps; each consumes arow[k] then reloads it for window wi+1
    STEP(buf, 0) STEP(buf, 1) STEP(buf, 2) STEP(buf, 3)
    STEP(buf, 4) STEP(buf, 5) STEP(buf, 6) STEP(buf, 7)

    // ead staging write
    eadbuf[nb][w][v] = (v2f){e_st.x, e_st.y};
    q1 = q2; r1 = r2;

    LGKM_BARRIER();   // drains LDS ops AND this window's s_loads
    SCHED_FENCE();
  }

  // ---- tail: window 62 = steps 496..499, buf 0 (arow loaded in window 61) ----
  {
    uint32_t onext0, onext1, onext2, onext3;
    {
      int4 p0 = *(const int4*)&sidx_a[504];   // clamped entries, harmless reloads
      onext0 = RL(p0.x + wb); onext1 = RL(p0.y + wb);
      onext2 = RL(p0.z + wb); onext3 = RL(p0.w + wb);
    }
    edr[0] = eadbuf[0][0][v];
    edr[1] = eadbuf[0][1][v];
    FLUSH(1, (NWIN - 1) * WIN);              // flush window 61
    STEP(0, 0) STEP(0, 1) STEP(0, 2) STEP(0, 3)
    LGKM_BARRIER();
    SCHED_FENCE();
    if (w < (SS - NWIN * WIN)) {
      float sum = 0.f;
#pragma unroll
      for (int wv = 0; wv < NW; ++wv) sum += red[0][w][wv][v];
      outp[(size_t)(NWIN * WIN + w) * 64 + v] = sum;
    }
  }
#undef STEP
#undef FLUSH
}

// ---------------- kernel 3: summary + logits + softmax ----------------
__global__ __launch_bounds__(64) void k_out(
    const float* __restrict__ reads, const int* __restrict__ qs,
    const float* __restrict__ sq_tab, const float* __restrict__ WsT,
    const float* __restrict__ bs, const float* __restrict__ WcT,
    const float* __restrict__ bc,
    float* __restrict__ out_logits, float* __restrict__ out_probs) {
  __shared__ float xs[64 * 65];
  const int lane = threadIdx.x;
  const long rowbase = (long)blockIdx.x * 64;
  const float* __restrict__ src = reads + rowbase * 64;

#pragma unroll 8
  for (int it = 0; it < 64; ++it)
    xs[it * 65 + lane] = src[it * 64 + lane];
  __syncthreads();

  float x[64];
#pragma unroll
  for (int i = 0; i < 64; ++i) x[i] = xs[lane * 65 + i];

  const long row = rowbase + lane;
  const int q = qs[row];
  const float* __restrict__ sqrow = sq_tab + (long)q * 64;

  float sm[SD];
#pragma unroll
  for (int j = 0; j < SD; ++j) {
    float acc = bs[j] + sqrow[j];
    const float* __restrict__ wrow = WsT + j * 64;  // uniform -> s_load
#pragma unroll
    for (int i = 0; i < 64; ++i) acc = fmaf(x[i], wrow[i], acc);
    float ex = __expf(2.f * acc);
    sm[j] = (ex - 1.f) / (ex + 1.f);
  }

  float lg[KK];
#pragma unroll
  for (int c = 0; c < KK; ++c) {
    float acc = bc[c];
    const float* __restrict__ wrow = WcT + c * SD;  // uniform -> s_load
#pragma unroll
    for (int j = 0; j < SD; ++j) acc = fmaf(sm[j], wrow[j], acc);
    lg[c] = acc;
  }

  float mx = lg[0];
#pragma unroll
  for (int c = 1; c < KK; ++c) mx = fmaxf(mx, lg[c]);
  float p[KK], sum = 0.f;
#pragma unroll
  for (int c = 0; c < KK; ++c) { p[c] = __expf(lg[c] - mx); sum += p[c]; }
  float inv = 1.f / sum;
#pragma unroll
  for (int c = 0; c < KK; ++c) {
    out_logits[row * KK + c] = lg[c];
    out_probs[row * KK + c] = p[c] * inv;
  }
}

extern "C" void kernel_launch(void* const* d_in, const int* in_sizes, int n_in,
                              void* d_out, int out_size, void* d_ws, size_t ws_size,
                              hipStream_t stream) {
  const int*   questions  = (const int*)  d_in[0];
  const int*   responses  = (const int*)  d_in[1];
  const float* q_table    = (const float*)d_in[2];
  const float* item_table = (const float*)d_in[3];
  const float* Wv         = (const float*)d_in[4];
  const float* bv         = (const float*)d_in[5];
  const float* key_mem    = (const float*)d_in[6];
  const float* init_vm    = (const float*)d_in[7];
  const float* We         = (const float*)d_in[8];
  const float* be         = (const float*)d_in[9];
  const float* Wa         = (const float*)d_in[10];
  const float* ba         = (const float*)d_in[11];
  const float* Ws         = (const float*)d_in[12];
  const float* bs         = (const float*)d_in[13];
  const float* Wc         = (const float*)d_in[14];
  const float* bc         = (const float*)d_in[15];

  float* ws       = (float*)d_ws;
  float* attn_tab = ws + OFF_ATTN;
  float* sq_tab   = ws + OFF_SQ;
  float* ead_tab  = ws + OFF_EAD;
  float* WsT      = ws + OFF_WST;
  float* WcT      = ws + OFF_WCT;
  float* reads    = ws + OFF_READS;

  float* out_logits = (float*)d_out;
  float* out_probs  = out_logits + (size_t)BB * SS * KK;

  hipLaunchKernelGGL(k_tabs, dim3(NQ1 + 1 + NQ1 * KK), dim3(64), 0, stream,
                     q_table, item_table, key_mem, Wv, bv, We, be, Wa, ba, Ws, Wc,
                     attn_tab, sq_tab, ead_tab, WsT, WcT);
  hipLaunchKernelGGL(k_scan, dim3(BB), dim3(NW * 64), 0, stream,
                     questions, responses, attn_tab, ead_tab, init_vm, reads);
  hipLaunchKernelGGL(k_out, dim3(BB * SS / 64), dim3(64), 0, stream,
                     reads, questions, sq_tab, WsT, bs, WcT, bc,
                     out_logits, out_probs);
}